// Round 17
// baseline (97.167 us; speedup 1.0000x reference)
//
#include <hip/hip_runtime.h>
#include <hip/hip_bf16.h>
#include <math.h>

#define BDIM 4096
#define DDIM 2048
#define PDIM 128
#define CDIM 10
#define TB   8192   // 2*B

// exp(cos/TEMP) with TEMP=0.5  ->  exp2(cos * 2/ln2)
#define EXP_SCALE 2.8853900817779268f
#define LAMBDA 0.2f
#define EPS 1e-8f

typedef __bf16 bfv8 __attribute__((ext_vector_type(8)));
typedef float  fv4  __attribute__((ext_vector_type(4)));
typedef unsigned short usv8 __attribute__((ext_vector_type(8)));

__device__ __forceinline__ unsigned short f2bf(float f) {
    unsigned int u = __float_as_uint(f);
    u += 0x7FFFu + ((u >> 16) & 1u);      // round-to-nearest-even
    return (unsigned short)(u >> 16);
}

// Fragment order: 16x32 bf16 operand tile stored as 64 lanes x 8 elems (1 KB):
// lane l (l15,lg), elem j holds M[row l15][k lg*8+j].
//
// ws layout (float index) — PEAK 4.016 MB (R14-proven size):
//  [0]           sup_acc
//  [1]           flag (int)
//  [16 ..)       phat_f  512 grp x 4 ks x 512 bf16 (2 MB)      [16, 524304)
//  [524304 ..)   WpTf 131072 + WcTf 16384 floats (576 KB)      [524304, 671760)
//  [524304 ..)   part [64][8192] f32 (2 MB) — OVERLAPS weights (dead after k13)
//  [1048592 ..)  pospart [32][128] f32 (16 KB)

// ---------------- kf: label-layout flag + zero scalar accumulators ----------
__global__ void kf_flag(const int* __restrict__ y32, int* __restrict__ flag_out,
                        float* __restrict__ ws_f, float* __restrict__ out) {
    __shared__ int s_ok;
    if (threadIdx.x == 0) s_ok = 1;
    __syncthreads();
    int ok = 1;
    #pragma unroll
    for (int i = 0; i < 8; ++i) {
        int w = 2 * (threadIdx.x + 256 * i) + 1;   // odd words 1..4095
        if (y32[w] != 0) ok = 0;
    }
    if (!ok) atomicAnd(&s_ok, 0);
    __syncthreads();
    if (threadIdx.x == 0) { *flag_out = s_ok; ws_f[0] = 0.0f; out[0] = 0.0f; }
}

// ---------------- kw: build fragment-ordered bf16 weights ----------------
__global__ __launch_bounds__(256) void kw_prep(
    const float* __restrict__ Wp, const float* __restrict__ Wc,
    unsigned short* __restrict__ WpTf, unsigned short* __restrict__ WcTf)
{
    int idx = blockIdx.x * 256 + threadIdx.x;   // < 36864
    if (idx < 32768) {
        const int l = idx & 63, frag = idx >> 6;
        const int n = frag >> 6, ks2 = frag & 63;
        const int l15 = l & 15, lg = l >> 4;
        usv8 o;
        #pragma unroll
        for (int j = 0; j < 8; ++j)
            o[j] = f2bf(Wp[(size_t)(ks2 * 32 + lg * 8 + j) * PDIM + n * 16 + l15]);
        *(usv8*)&WpTf[(size_t)idx * 8] = o;
    } else {
        const int i2 = idx - 32768;             // < 4096
        const int l = i2 & 63, ks2 = i2 >> 6;
        const int l15 = l & 15, lg = l >> 4;
        usv8 o;
        #pragma unroll
        for (int j = 0; j < 8; ++j)
            o[j] = (l15 < CDIM) ? f2bf(Wc[(size_t)(ks2 * 32 + lg * 8 + j) * CDIM + l15])
                                : (unsigned short)0;
        *(usv8*)&WcTf[(size_t)i2 * 8] = o;
    }
}

// ---------------- k13: fused proj-GEMM + normalize + digits + CE -----------
// NO LDS STAGING, NO K-LOOP BARRIERS. 512 blocks x 256 thr (4 waves);
// block = one 16-row fragment group g = blockIdx.x. Per ks2 iteration:
// A-frag loaded DIRECTLY from x (2 contiguous float4/lane + f2bf — the
// R4/R6-proven conversion path; all 4 waves share addresses -> L1 bcast);
// B-frags are 1 KB coalesced loads from fragment-ordered WpTf (R11-proven).
// Waves run free — latency hidden by per-wave ILP + 8 drifting waves/CU,
// instead of 8 waves lockstepped on a vmcnt(0)-draining barrier (the
// invariant behind five ~40 µs k13 variants, R9-R16).
// Wave wv: proj n-groups 2wv,2wv+1; digits slices ks2>>4 == wv (16 each).
__global__ __launch_bounds__(256) void k13_fused(
    const float* __restrict__ xi, const float* __restrict__ xj,
    const __bf16* __restrict__ WpTf, const __bf16* __restrict__ WcTf,
    const int* __restrict__ y, const int* __restrict__ flag_p,
    unsigned short* __restrict__ phat_f, float* __restrict__ sup_acc)
{
    __shared__ float sproj[16][132];            // 8.4 KB
    __shared__ float sdig[4][16][16];           // 4 KB
    __shared__ float sce[16];

    const int tid = threadIdx.x;
    const int wv = tid >> 6, lane = tid & 63;
    const int l15 = lane & 15, lg = lane >> 4;
    const int R0 = blockIdx.x * 16;
    const float* src = (R0 < BDIM) ? (xi + (size_t)R0 * DDIM)
                                   : (xj + (size_t)(R0 - BDIM) * DDIM);
    const float* xrow = src + (size_t)l15 * DDIM + lg * 8;
    const __bf16* bp0 = WpTf + (size_t)((2 * wv) * 64) * 512 + lane * 8;
    const __bf16* bp1 = WpTf + (size_t)((2 * wv + 1) * 64) * 512 + lane * 8;

    fv4 acc0 = {}, acc1 = {}, accd = {};

    #pragma unroll 4
    for (int ks2 = 0; ks2 < 64; ++ks2) {
        float4 x0 = *(const float4*)(xrow + ks2 * 32);
        float4 x1 = *(const float4*)(xrow + ks2 * 32 + 4);
        bfv8 b0 = *(const bfv8*)(bp0 + (size_t)ks2 * 512);
        bfv8 b1 = *(const bfv8*)(bp1 + (size_t)ks2 * 512);
        usv8 au;
        au[0] = f2bf(x0.x); au[1] = f2bf(x0.y);
        au[2] = f2bf(x0.z); au[3] = f2bf(x0.w);
        au[4] = f2bf(x1.x); au[5] = f2bf(x1.y);
        au[6] = f2bf(x1.z); au[7] = f2bf(x1.w);
        bfv8 a = __builtin_bit_cast(bfv8, au);
        acc0 = __builtin_amdgcn_mfma_f32_16x16x32_bf16(a, b0, acc0, 0, 0, 0);
        acc1 = __builtin_amdgcn_mfma_f32_16x16x32_bf16(a, b1, acc1, 0, 0, 0);
        if ((ks2 >> 4) == wv) {    // wave-uniform; 16 slices per wave, union=64
            bfv8 bd = *(const bfv8*)(WcTf + (size_t)ks2 * 512 + lane * 8);
            accd = __builtin_amdgcn_mfma_f32_16x16x32_bf16(a, bd, accd, 0, 0, 0);
        }
    }

    // scatter: wave wv owns cols [wv*32, wv*32+32); C layout row=lg*4+r, col=l15
    #pragma unroll
    for (int r = 0; r < 4; ++r) {
        sproj[lg * 4 + r][wv * 32 + l15]      = acc0[r];
        sproj[lg * 4 + r][wv * 32 + 16 + l15] = acc1[r];
    }
    #pragma unroll
    for (int r = 0; r < 4; ++r)
        sdig[wv][lg * 4 + r][l15] = accd[r];
    __syncthreads();

    // ---- proj: rsqrt-normalize rows, write bf16 phat (fragment order) ----
    {
        const int row = tid >> 4;            // 0..15, 16 threads per row
        const int c8  = (tid & 15) * 8;
        fv4 p0 = *(const fv4*)&sproj[row][c8];
        fv4 p1 = *(const fv4*)&sproj[row][c8 + 4];
        float ssq = p0[0]*p0[0] + p0[1]*p0[1] + p0[2]*p0[2] + p0[3]*p0[3]
                  + p1[0]*p1[0] + p1[1]*p1[1] + p1[2]*p1[2] + p1[3]*p1[3];
        #pragma unroll
        for (int m = 8; m >= 1; m >>= 1) ssq += __shfl_xor(ssq, m, 64);
        float rn = rsqrtf(ssq);
        usv8 pk;
        pk[0] = f2bf(p0[0]*rn); pk[1] = f2bf(p0[1]*rn);
        pk[2] = f2bf(p0[2]*rn); pk[3] = f2bf(p0[3]*rn);
        pk[4] = f2bf(p1[0]*rn); pk[5] = f2bf(p1[1]*rn);
        pk[6] = f2bf(p1[2]*rn); pk[7] = f2bf(p1[3]*rn);
        const int ks = c8 >> 5, lgw = (c8 >> 3) & 3;
        *(usv8*)&phat_f[(size_t)(((size_t)blockIdx.x * 4 + ks) * 512 + (lgw * 16 + row) * 8)] = pk;
    }

    // ---- digits: sum 4 wave-slabs, CE via 16-lane shuffles ----
    {
        const int drow = tid >> 4;           // 0..15
        const int dc   = tid & 15;           // cols 10..15 zero-pad
        float d = 0.0f;
        #pragma unroll
        for (int w = 0; w < 4; ++w) d += sdig[w][drow][dc];
        float dv = (dc < CDIM) ? d : -1e30f;
        float mx = dv;
        #pragma unroll
        for (int m = 8; m >= 1; m >>= 1) mx = fmaxf(mx, __shfl_xor(mx, m, 64));
        float e = (dc < CDIM) ? __expf(d - mx) : 0.0f;
        float s = e;
        #pragma unroll
        for (int m = 8; m >= 1; m >>= 1) s += __shfl_xor(s, m, 64);
        const int rowg = R0 + drow;
        const int idx  = rowg & (BDIM - 1);
        const int label = (*flag_p) ? y[2 * idx] : y[idx];
        float dl = (dc == label) ? d : 0.0f;
        #pragma unroll
        for (int m = 8; m >= 1; m >>= 1) dl += __shfl_xor(dl, m, 64);
        if (dc == 0) sce[drow] = (mx + __logf(s)) - dl;
    }
    __syncthreads();
    if (tid == 0) {
        float t = 0.0f;
        #pragma unroll
        for (int r = 0; r < 16; ++r) t += sce[r];
        atomicAdd(sup_acc, t * (1.0f / BDIM));
    }
}

// ---------------- k3: Gram row-sum via bf16 MFMA (upper-triangle tiles) ----
// Unchanged from R16 (XCD-swizzled, atomic-free part/pospart stores).
__global__ __launch_bounds__(256) void k3_gram_mfma(
    const __bf16* __restrict__ pf,
    float* __restrict__ part, float* __restrict__ pospart)
{
    __shared__ float srow[128 * 37 + 4];   // [row][wc*16+l15], stride 37
    __shared__ float scol[128 * 9 + 4];    // [col][wr*4+lg],  stride 9
    __shared__ float spos[128];
    const int tid = threadIdx.x;

    int t = (blockIdx.x & 7) * 260 + (blockIdx.x >> 3);   // XCD swizzle
    int ti = 0;
    while (t >= 64 - ti) { t -= 64 - ti; ++ti; }
    const int tj = ti + t;
    const int I0 = ti * 128, J0 = tj * 128;
    const bool diag    = (ti == tj);
    const bool partner = (tj == ti + 32);

    if (tid < 128) spos[tid] = 0.0f;
    __syncthreads();

    const int wid = tid >> 6, lane = tid & 63;
    const int wr = wid >> 1, wc = wid & 1;
    const int l15 = lane & 15, lg = lane >> 4;

    fv4 acc[4][4] = {};
    #pragma unroll
    for (int ks = 0; ks < 4; ++ks) {
        bfv8 a[4], b[4];
        #pragma unroll
        for (int m = 0; m < 4; ++m)
            a[m] = *(const bfv8*)(pf + (size_t)(((ti * 8 + wr * 4 + m) * 4 + ks) * 512) + lane * 8);
        #pragma unroll
        for (int n = 0; n < 4; ++n)
            b[n] = *(const bfv8*)(pf + (size_t)(((tj * 8 + wc * 4 + n) * 4 + ks) * 512) + lane * 8);
        #pragma unroll
        for (int m = 0; m < 4; ++m)
            #pragma unroll
            for (int n = 0; n < 4; ++n)
                acc[m][n] = __builtin_amdgcn_mfma_f32_16x16x32_bf16(a[m], b[n], acc[m][n], 0, 0, 0);
    }

    // epilogue: exp, diag-mask, per-lane row/col partials
    float rs_l[4][4];
    float cs_l[4] = {0, 0, 0, 0};
    #pragma unroll
    for (int m = 0; m < 4; ++m)
        #pragma unroll
        for (int r = 0; r < 4; ++r) rs_l[m][r] = 0.0f;

    #pragma unroll
    for (int m = 0; m < 4; ++m) {
        const int ribase = wr * 64 + m * 16 + lg * 4;
        #pragma unroll
        for (int n = 0; n < 4; ++n) {
            const int cj = wc * 64 + n * 16 + l15;
            #pragma unroll
            for (int r = 0; r < 4; ++r) {
                const int ri = ribase + r;
                float e = exp2f(acc[m][n][r] * EXP_SCALE);
                if (diag && ri == cj) e = 0.0f;
                rs_l[m][r] += e;
                cs_l[n] += e;
                if (partner && ri == cj) atomicAdd(&spos[ri], e);
            }
        }
    }

    // scatter partials (each slot written by exactly one lane)
    #pragma unroll
    for (int m = 0; m < 4; ++m)
        #pragma unroll
        for (int r = 0; r < 4; ++r)
            srow[(wr * 64 + m * 16 + lg * 4 + r) * 37 + wc * 16 + l15] = rs_l[m][r];
    #pragma unroll
    for (int n = 0; n < 4; ++n)
        scol[(wc * 64 + n * 16 + l15) * 9 + wr * 4 + lg] = cs_l[n];
    __syncthreads();

    // gather + plain stores (no global atomics; single writer per slot)
    if (tid < 128) {
        float s = 0.0f;
        #pragma unroll
        for (int q = 0; q < 32; ++q) s += srow[tid * 37 + q];
        part[(size_t)tj * TB + I0 + tid] = s;
        if (partner) pospart[ti * 128 + tid] = spos[tid];
    } else if (!diag) {
        const int col = tid - 128;
        float s = 0.0f;
        #pragma unroll
        for (int q = 0; q < 8; ++q) s += scol[col * 9 + q];
        part[(size_t)ti * TB + J0 + col] = s;
    }
}

// ---------------- k4: gather partials + final reduction (32 blocks) --------
__global__ __launch_bounds__(256) void k4_final(
    const float* __restrict__ part, const float* __restrict__ pospart,
    const float* __restrict__ sup_acc, float* __restrict__ out)
{
    __shared__ float red[4];
    const int tid = threadIdx.x;
    const int r = blockIdx.x * 256 + tid;
    float rs = 0.0f;
    #pragma unroll 8
    for (int t = 0; t < 64; ++t) rs += part[(size_t)t * TB + r];
    const float pos = pospart[((r & (BDIM - 1)) >> 7) * 128 + (r & 127)];
    float s = -__logf(pos / rs + EPS);
    #pragma unroll
    for (int m = 32; m >= 1; m >>= 1) s += __shfl_xor(s, m, 64);
    if ((tid & 63) == 0) red[tid >> 6] = s;
    __syncthreads();
    if (tid == 0) {
        float p = (red[0] + red[1] + red[2] + red[3]) * (1.0f / TB);
        if (blockIdx.x == 0) p += LAMBDA * sup_acc[0];
        atomicAdd(out, p);
    }
}

extern "C" void kernel_launch(void* const* d_in, const int* in_sizes, int n_in,
                              void* d_out, int out_size, void* d_ws, size_t ws_size,
                              hipStream_t stream) {
    const float* xi = (const float*)d_in[1];
    const float* xj = (const float*)d_in[2];
    const int*   y  = (const int*)d_in[3];
    const float* Wp = (const float*)d_in[4];
    const float* Wc = (const float*)d_in[5];
    float* out  = (float*)d_out;

    float* ws_f   = (float*)d_ws;
    float* sup    = ws_f;
    int*   flag   = (int*)(ws_f + 1);
    unsigned short* phat_u = (unsigned short*)(ws_f + 16);
    unsigned short* WpTf_u = (unsigned short*)(ws_f + 524304);
    unsigned short* WcTf_u = (unsigned short*)(ws_f + 655376);
    float* part    = ws_f + 524304;     // overlaps weights (dead after k13)
    float* pospart = ws_f + 1048592;

    kf_flag<<<1, 256, 0, stream>>>(y, flag, ws_f, out);
    kw_prep<<<144, 256, 0, stream>>>(Wp, Wc, WpTf_u, WcTf_u);
    k13_fused<<<512, 256, 0, stream>>>(xi, xj, (const __bf16*)WpTf_u, (const __bf16*)WcTf_u,
                                       y, flag, phat_u, sup);
    k3_gram_mfma<<<2080, 256, 0, stream>>>((const __bf16*)phat_u, part, pospart);
    k4_final<<<32, 256, 0, stream>>>(part, pospart, sup, out);
}

// Round 18
// 84.232 us; speedup vs baseline: 1.1536x; 1.1536x over previous
//
#include <hip/hip_runtime.h>
#include <hip/hip_bf16.h>
#include <math.h>

#define BDIM 4096
#define DDIM 2048
#define PDIM 128
#define CDIM 10
#define TB   8192   // 2*B

// exp(cos/TEMP) with TEMP=0.5  ->  exp2(cos * 2/ln2)
#define EXP_SCALE 2.8853900817779268f
#define LAMBDA 0.2f
#define EPS 1e-8f

typedef __bf16 bfv8 __attribute__((ext_vector_type(8)));
typedef float  fv4  __attribute__((ext_vector_type(4)));
typedef unsigned short usv8 __attribute__((ext_vector_type(8)));

__device__ __forceinline__ unsigned short f2bf(float f) {
    unsigned int u = __float_as_uint(f);
    u += 0x7FFFu + ((u >> 16) & 1u);      // round-to-nearest-even
    return (unsigned short)(u >> 16);
}

// Fragment order: 16x32 bf16 operand tile stored as 64 lanes x 8 elems (1 KB):
// lane l (l15,lg), elem j holds M[row l15][k lg*8+j].
//
// ws layout (float index) — PEAK 4.016 MB (R14-proven size):
//  [0]           sup_acc
//  [1]           flag (int)
//  [16 ..)       phat_f  512 grp x 4 ks x 512 bf16 (2 MB)      [16, 524304)
//  [524304 ..)   WpTf 131072 + WcTf 16384 floats (576 KB)      [524304, 671760)
//  [524304 ..)   part [64][8192] f32 (2 MB) — OVERLAPS weights (dead after k13)
//  [1048592 ..)  pospart [32][128] f32 (16 KB)

// ---------------- kf: label-layout flag + zero scalar accumulators ----------
__global__ void kf_flag(const int* __restrict__ y32, int* __restrict__ flag_out,
                        float* __restrict__ ws_f, float* __restrict__ out) {
    __shared__ int s_ok;
    if (threadIdx.x == 0) s_ok = 1;
    __syncthreads();
    int ok = 1;
    #pragma unroll
    for (int i = 0; i < 8; ++i) {
        int w = 2 * (threadIdx.x + 256 * i) + 1;   // odd words 1..4095
        if (y32[w] != 0) ok = 0;
    }
    if (!ok) atomicAnd(&s_ok, 0);
    __syncthreads();
    if (threadIdx.x == 0) { *flag_out = s_ok; ws_f[0] = 0.0f; out[0] = 0.0f; }
}

// ---------------- kw: build fragment-ordered bf16 weights ----------------
__global__ __launch_bounds__(256) void kw_prep(
    const float* __restrict__ Wp, const float* __restrict__ Wc,
    unsigned short* __restrict__ WpTf, unsigned short* __restrict__ WcTf)
{
    int idx = blockIdx.x * 256 + threadIdx.x;   // < 36864
    if (idx < 32768) {
        const int l = idx & 63, frag = idx >> 6;
        const int n = frag >> 6, ks2 = frag & 63;
        const int l15 = l & 15, lg = l >> 4;
        usv8 o;
        #pragma unroll
        for (int j = 0; j < 8; ++j)
            o[j] = f2bf(Wp[(size_t)(ks2 * 32 + lg * 8 + j) * PDIM + n * 16 + l15]);
        *(usv8*)&WpTf[(size_t)idx * 8] = o;
    } else {
        const int i2 = idx - 32768;             // < 4096
        const int l = i2 & 63, ks2 = i2 >> 6;
        const int l15 = l & 15, lg = l >> 4;
        usv8 o;
        #pragma unroll
        for (int j = 0; j < 8; ++j)
            o[j] = (l15 < CDIM) ? f2bf(Wc[(size_t)(ks2 * 32 + lg * 8 + j) * CDIM + l15])
                                : (unsigned short)0;
        *(usv8*)&WcTf[(size_t)i2 * 8] = o;
    }
}

// ---------------- k13: fused proj-GEMM + normalize + digits + CE -----------
// R17 structure (no LDS, no K-loop barriers; indices identical) with the
// REGISTER-ILP fix: launch_bounds(256,2) lifts the VGPR cap (R17's default
// occupancy target gave VGPR=28 -> fully serialized loads; k13 time has
// tracked VGPR across the session: 88->39us, 52->41us, 28->77us).
// K-loop split into 16 chunks of 4 ks2: load phase fills named arrays
// (8 float4 A + 8 bfv8 B + 4 digit frags issued back-to-back), MFMA phase
// consumes — ~16 loads in flight per wave.
__global__ __launch_bounds__(256, 2) void k13_fused(
    const float* __restrict__ xi, const float* __restrict__ xj,
    const __bf16* __restrict__ WpTf, const __bf16* __restrict__ WcTf,
    const int* __restrict__ y, const int* __restrict__ flag_p,
    unsigned short* __restrict__ phat_f, float* __restrict__ sup_acc)
{
    __shared__ float sproj[16][132];            // 8.4 KB
    __shared__ float sdig[4][16][16];           // 4 KB
    __shared__ float sce[16];

    const int tid = threadIdx.x;
    const int wv = tid >> 6, lane = tid & 63;
    const int l15 = lane & 15, lg = lane >> 4;
    const int R0 = blockIdx.x * 16;
    const float* src = (R0 < BDIM) ? (xi + (size_t)R0 * DDIM)
                                   : (xj + (size_t)(R0 - BDIM) * DDIM);
    const float* xrow = src + (size_t)l15 * DDIM + lg * 8;
    const __bf16* bp0 = WpTf + (size_t)((2 * wv) * 64) * 512 + lane * 8;
    const __bf16* bp1 = WpTf + (size_t)((2 * wv + 1) * 64) * 512 + lane * 8;

    fv4 acc0 = {}, acc1 = {}, accd = {};

    for (int c = 0; c < 16; ++c) {              // 16 chunks x 4 ks2
        const bool dig = ((c >> 2) == wv);      // == (ks2>>4)==wv for s<4

        // ---- load phase: all chunk operands issued back-to-back ----
        float4 xa0[4], xa1[4];
        bfv8 b0[4], b1[4];
        bfv8 bdv[4] = {};
        #pragma unroll
        for (int s = 0; s < 4; ++s) {
            const int ks2 = c * 4 + s;
            xa0[s] = *(const float4*)(xrow + ks2 * 32);
            xa1[s] = *(const float4*)(xrow + ks2 * 32 + 4);
            b0[s]  = *(const bfv8*)(bp0 + (size_t)ks2 * 512);
            b1[s]  = *(const bfv8*)(bp1 + (size_t)ks2 * 512);
        }
        if (dig) {
            #pragma unroll
            for (int s = 0; s < 4; ++s)
                bdv[s] = *(const bfv8*)(WcTf + (size_t)(c * 4 + s) * 512 + lane * 8);
        }

        // ---- compute phase ----
        #pragma unroll
        for (int s = 0; s < 4; ++s) {
            usv8 au;
            au[0] = f2bf(xa0[s].x); au[1] = f2bf(xa0[s].y);
            au[2] = f2bf(xa0[s].z); au[3] = f2bf(xa0[s].w);
            au[4] = f2bf(xa1[s].x); au[5] = f2bf(xa1[s].y);
            au[6] = f2bf(xa1[s].z); au[7] = f2bf(xa1[s].w);
            bfv8 a = __builtin_bit_cast(bfv8, au);
            acc0 = __builtin_amdgcn_mfma_f32_16x16x32_bf16(a, b0[s], acc0, 0, 0, 0);
            acc1 = __builtin_amdgcn_mfma_f32_16x16x32_bf16(a, b1[s], acc1, 0, 0, 0);
            if (dig)
                accd = __builtin_amdgcn_mfma_f32_16x16x32_bf16(a, bdv[s], accd, 0, 0, 0);
        }
    }

    // scatter: wave wv owns cols [wv*32, wv*32+32); C layout row=lg*4+r, col=l15
    #pragma unroll
    for (int r = 0; r < 4; ++r) {
        sproj[lg * 4 + r][wv * 32 + l15]      = acc0[r];
        sproj[lg * 4 + r][wv * 32 + 16 + l15] = acc1[r];
    }
    #pragma unroll
    for (int r = 0; r < 4; ++r)
        sdig[wv][lg * 4 + r][l15] = accd[r];
    __syncthreads();

    // ---- proj: rsqrt-normalize rows, write bf16 phat (fragment order) ----
    {
        const int row = tid >> 4;            // 0..15, 16 threads per row
        const int c8  = (tid & 15) * 8;
        fv4 p0 = *(const fv4*)&sproj[row][c8];
        fv4 p1 = *(const fv4*)&sproj[row][c8 + 4];
        float ssq = p0[0]*p0[0] + p0[1]*p0[1] + p0[2]*p0[2] + p0[3]*p0[3]
                  + p1[0]*p1[0] + p1[1]*p1[1] + p1[2]*p1[2] + p1[3]*p1[3];
        #pragma unroll
        for (int m = 8; m >= 1; m >>= 1) ssq += __shfl_xor(ssq, m, 64);
        float rn = rsqrtf(ssq);
        usv8 pk;
        pk[0] = f2bf(p0[0]*rn); pk[1] = f2bf(p0[1]*rn);
        pk[2] = f2bf(p0[2]*rn); pk[3] = f2bf(p0[3]*rn);
        pk[4] = f2bf(p1[0]*rn); pk[5] = f2bf(p1[1]*rn);
        pk[6] = f2bf(p1[2]*rn); pk[7] = f2bf(p1[3]*rn);
        const int ks = c8 >> 5, lgw = (c8 >> 3) & 3;
        *(usv8*)&phat_f[(size_t)(((size_t)blockIdx.x * 4 + ks) * 512 + (lgw * 16 + row) * 8)] = pk;
    }

    // ---- digits: sum 4 wave-slabs, CE via 16-lane shuffles ----
    {
        const int drow = tid >> 4;           // 0..15
        const int dc   = tid & 15;           // cols 10..15 zero-pad
        float d = 0.0f;
        #pragma unroll
        for (int w = 0; w < 4; ++w) d += sdig[w][drow][dc];
        float dv = (dc < CDIM) ? d : -1e30f;
        float mx = dv;
        #pragma unroll
        for (int m = 8; m >= 1; m >>= 1) mx = fmaxf(mx, __shfl_xor(mx, m, 64));
        float e = (dc < CDIM) ? __expf(d - mx) : 0.0f;
        float s = e;
        #pragma unroll
        for (int m = 8; m >= 1; m >>= 1) s += __shfl_xor(s, m, 64);
        const int rowg = R0 + drow;
        const int idx  = rowg & (BDIM - 1);
        const int label = (*flag_p) ? y[2 * idx] : y[idx];
        float dl = (dc == label) ? d : 0.0f;
        #pragma unroll
        for (int m = 8; m >= 1; m >>= 1) dl += __shfl_xor(dl, m, 64);
        if (dc == 0) sce[drow] = (mx + __logf(s)) - dl;
    }
    __syncthreads();
    if (tid == 0) {
        float t = 0.0f;
        #pragma unroll
        for (int r = 0; r < 16; ++r) t += sce[r];
        atomicAdd(sup_acc, t * (1.0f / BDIM));
    }
}

// ---------------- k3: Gram row-sum via bf16 MFMA (upper-triangle tiles) ----
// Unchanged (XCD-swizzled, atomic-free part/pospart stores).
__global__ __launch_bounds__(256) void k3_gram_mfma(
    const __bf16* __restrict__ pf,
    float* __restrict__ part, float* __restrict__ pospart)
{
    __shared__ float srow[128 * 37 + 4];   // [row][wc*16+l15], stride 37
    __shared__ float scol[128 * 9 + 4];    // [col][wr*4+lg],  stride 9
    __shared__ float spos[128];
    const int tid = threadIdx.x;

    int t = (blockIdx.x & 7) * 260 + (blockIdx.x >> 3);   // XCD swizzle
    int ti = 0;
    while (t >= 64 - ti) { t -= 64 - ti; ++ti; }
    const int tj = ti + t;
    const int I0 = ti * 128, J0 = tj * 128;
    const bool diag    = (ti == tj);
    const bool partner = (tj == ti + 32);

    if (tid < 128) spos[tid] = 0.0f;
    __syncthreads();

    const int wid = tid >> 6, lane = tid & 63;
    const int wr = wid >> 1, wc = wid & 1;
    const int l15 = lane & 15, lg = lane >> 4;

    fv4 acc[4][4] = {};
    #pragma unroll
    for (int ks = 0; ks < 4; ++ks) {
        bfv8 a[4], b[4];
        #pragma unroll
        for (int m = 0; m < 4; ++m)
            a[m] = *(const bfv8*)(pf + (size_t)(((ti * 8 + wr * 4 + m) * 4 + ks) * 512) + lane * 8);
        #pragma unroll
        for (int n = 0; n < 4; ++n)
            b[n] = *(const bfv8*)(pf + (size_t)(((tj * 8 + wc * 4 + n) * 4 + ks) * 512) + lane * 8);
        #pragma unroll
        for (int m = 0; m < 4; ++m)
            #pragma unroll
            for (int n = 0; n < 4; ++n)
                acc[m][n] = __builtin_amdgcn_mfma_f32_16x16x32_bf16(a[m], b[n], acc[m][n], 0, 0, 0);
    }

    // epilogue: exp, diag-mask, per-lane row/col partials
    float rs_l[4][4];
    float cs_l[4] = {0, 0, 0, 0};
    #pragma unroll
    for (int m = 0; m < 4; ++m)
        #pragma unroll
        for (int r = 0; r < 4; ++r) rs_l[m][r] = 0.0f;

    #pragma unroll
    for (int m = 0; m < 4; ++m) {
        const int ribase = wr * 64 + m * 16 + lg * 4;
        #pragma unroll
        for (int n = 0; n < 4; ++n) {
            const int cj = wc * 64 + n * 16 + l15;
            #pragma unroll
            for (int r = 0; r < 4; ++r) {
                const int ri = ribase + r;
                float e = exp2f(acc[m][n][r] * EXP_SCALE);
                if (diag && ri == cj) e = 0.0f;
                rs_l[m][r] += e;
                cs_l[n] += e;
                if (partner && ri == cj) atomicAdd(&spos[ri], e);
            }
        }
    }

    // scatter partials (each slot written by exactly one lane)
    #pragma unroll
    for (int m = 0; m < 4; ++m)
        #pragma unroll
        for (int r = 0; r < 4; ++r)
            srow[(wr * 64 + m * 16 + lg * 4 + r) * 37 + wc * 16 + l15] = rs_l[m][r];
    #pragma unroll
    for (int n = 0; n < 4; ++n)
        scol[(wc * 64 + n * 16 + l15) * 9 + wr * 4 + lg] = cs_l[n];
    __syncthreads();

    // gather + plain stores (no global atomics; single writer per slot)
    if (tid < 128) {
        float s = 0.0f;
        #pragma unroll
        for (int q = 0; q < 32; ++q) s += srow[tid * 37 + q];
        part[(size_t)tj * TB + I0 + tid] = s;
        if (partner) pospart[ti * 128 + tid] = spos[tid];
    } else if (!diag) {
        const int col = tid - 128;
        float s = 0.0f;
        #pragma unroll
        for (int q = 0; q < 8; ++q) s += scol[col * 9 + q];
        part[(size_t)ti * TB + J0 + col] = s;
    }
}

// ---------------- k4: gather partials + final reduction (32 blocks) --------
__global__ __launch_bounds__(256) void k4_final(
    const float* __restrict__ part, const float* __restrict__ pospart,
    const float* __restrict__ sup_acc, float* __restrict__ out)
{
    __shared__ float red[4];
    const int tid = threadIdx.x;
    const int r = blockIdx.x * 256 + tid;
    float rs = 0.0f;
    #pragma unroll 8
    for (int t = 0; t < 64; ++t) rs += part[(size_t)t * TB + r];
    const float pos = pospart[((r & (BDIM - 1)) >> 7) * 128 + (r & 127)];
    float s = -__logf(pos / rs + EPS);
    #pragma unroll
    for (int m = 32; m >= 1; m >>= 1) s += __shfl_xor(s, m, 64);
    if ((tid & 63) == 0) red[tid >> 6] = s;
    __syncthreads();
    if (tid == 0) {
        float p = (red[0] + red[1] + red[2] + red[3]) * (1.0f / TB);
        if (blockIdx.x == 0) p += LAMBDA * sup_acc[0];
        atomicAdd(out, p);
    }
}

extern "C" void kernel_launch(void* const* d_in, const int* in_sizes, int n_in,
                              void* d_out, int out_size, void* d_ws, size_t ws_size,
                              hipStream_t stream) {
    const float* xi = (const float*)d_in[1];
    const float* xj = (const float*)d_in[2];
    const int*   y  = (const int*)d_in[3];
    const float* Wp = (const float*)d_in[4];
    const float* Wc = (const float*)d_in[5];
    float* out  = (float*)d_out;

    float* ws_f   = (float*)d_ws;
    float* sup    = ws_f;
    int*   flag   = (int*)(ws_f + 1);
    unsigned short* phat_u = (unsigned short*)(ws_f + 16);
    unsigned short* WpTf_u = (unsigned short*)(ws_f + 524304);
    unsigned short* WcTf_u = (unsigned short*)(ws_f + 655376);
    float* part    = ws_f + 524304;     // overlaps weights (dead after k13)
    float* pospart = ws_f + 1048592;

    kf_flag<<<1, 256, 0, stream>>>(y, flag, ws_f, out);
    kw_prep<<<144, 256, 0, stream>>>(Wp, Wc, WpTf_u, WcTf_u);
    k13_fused<<<512, 256, 0, stream>>>(xi, xj, (const __bf16*)WpTf_u, (const __bf16*)WcTf_u,
                                       y, flag, phat_u, sup);
    k3_gram_mfma<<<2080, 256, 0, stream>>>((const __bf16*)phat_u, part, pospart);
    k4_final<<<32, 256, 0, stream>>>(part, pospart, sup, out);
}